// Round 1
// 273.852 us; speedup vs baseline: 1.0145x; 1.0145x over previous
//
#include <hip/hip_runtime.h>
#include <hip/hip_bf16.h>
#include <stdint.h>

#define M_TOK 32
#define IN_F 4096
#define OUT_F 11008
#define NSPLIT 8
#define KRANGE (IN_F / NSPLIT)   // 512 k per block
#define NSTEP  (KRANGE / 32)     // 16 MFMA k-steps per block

typedef __attribute__((ext_vector_type(8))) short bf16x8;
typedef __attribute__((ext_vector_type(4))) float f32x4;

__device__ inline uint32_t pack_bf16(float a, float b) {
    __hip_bfloat16 ha = __float2bfloat16(a);
    __hip_bfloat16 hb = __float2bfloat16(b);
    uint16_t ua = *(uint16_t*)&ha;
    uint16_t ub = *(uint16_t*)&hb;
    return (uint32_t)ua | ((uint32_t)ub << 16);
}

// out[m][o] = bias[o]   (grid: 43 x 32, block 256 — exact cover of 11008 x 32)
__global__ void init_out_kernel(const float* __restrict__ bias, float* __restrict__ out) {
    int o = blockIdx.x * 256 + threadIdx.x;
    int m = blockIdx.y;
    out[(size_t)m * OUT_F + o] = bias[o];
}

// LDS-staged streaming dequant-GEMM.
// Wave w of block (nb,ks): out rows [nb*64 + w*16, +16), k range [ks*512, +512).
// Weight tile [64 rows][32 k] int32 staged via global_load_lds (dwordx4) —
// per wave-instruction: 8 contiguous 128-B row segments (vs 64 scattered 16-B
// segments in the register-direct version).
// LDS 16-B chunk index XOR-swizzled with (row&7): applied on the GLOBAL SOURCE
// address (linear LDS dest — global_load_lds writes base+lane*16) and inverted
// on the ds_read side. Breaks the 16-way bank conflict of the 128-B row stride.
// Fragment contents per lane are identical to the verified register-direct
// kernel: lane holds W[n = base+(lane&15)][k = (lane>>4)*8 .. +8).
__launch_bounds__(256)
__global__ void qgemm_kernel(const float* __restrict__ x,
                             const int* __restrict__ wq,
                             const float* __restrict__ sz,
                             float* __restrict__ out) {
    __shared__ int lds_w[2][64 * 32];   // double-buffered 8-KB weight tiles

    const int bid = blockIdx.x;
    const int ks  = bid & (NSPLIT - 1);
    const int nb  = bid >> 3;
    const int t   = threadIdx.x;
    const int wv  = t >> 6;
    const int l   = t & 63;
    const int lm  = l & 15;
    const int lq  = l >> 4;

    const int row0 = nb * 64;
    const int row  = row0 + wv * 16 + lm;    // out-feature row this lane computes
    const int k0   = ks * KRANGE;

    // --- staging assignment: thread t covers tile row rs = (t>>3) (+32 for
    // issue 1), 16-B chunk slot cs = t&7. Fetch global chunk (cs ^ (rs&7)) so
    // that LDS slot c of row r holds global chunk c^(r&7) (involution).
    const int rs    = t >> 3;                // 0..31
    const int cs    = t & 7;
    const int* gw0  = wq + (size_t)(row0 + rs) * IN_F + k0 + ((cs ^ (rs & 7)) * 4);
    const int* gw1  = gw0 + (size_t)32 * IN_F;   // rows 32..63

#define STAGE(buf, soff) do {                                                   \
    __builtin_amdgcn_global_load_lds(                                           \
        (const __attribute__((address_space(1))) int*)(gw0 + (soff)),           \
        (__attribute__((address_space(3))) int*)&lds_w[(buf)][wv * 256],        \
        16, 0, 0);                                                              \
    __builtin_amdgcn_global_load_lds(                                           \
        (const __attribute__((address_space(1))) int*)(gw1 + (soff)),           \
        (__attribute__((address_space(3))) int*)&lds_w[(buf)][1024 + wv * 256], \
        16, 0, 0);                                                              \
} while (0)

    // --- reader addresses (swizzle inverted): lane wants global chunks
    // j0 = 2*lq (ints lq*8..+4) and j1 = 2*lq+1 (ints +4..+8) of row rloc.
    const int rloc = wv * 16 + lm;
    const int c0   = rloc * 32 + (((2 * lq)     ^ (rloc & 7)) * 4);
    const int c1   = rloc * 32 + (((2 * lq + 1) ^ (rloc & 7)) * 4);

    const float* xp0 = x + (size_t)lm * IN_F + k0 + lq * 8;
    const float* xp1 = xp0 + (size_t)16 * IN_F;
    const float* szp = sz + ((size_t)(k0 >> 5) * OUT_F + row) * 2;

    f32x4 acc0 = {0.f, 0.f, 0.f, 0.f};
    f32x4 acc1 = {0.f, 0.f, 0.f, 0.f};

    STAGE(0, 0);
    int cur = 0;
    #pragma unroll 2
    for (int s = 0; s < NSTEP; ++s) {
        __syncthreads();                    // drains vmcnt: buf[cur] is staged
        if (s + 1 < NSTEP) STAGE(cur ^ 1, (s + 1) * 32);   // prefetch next tile

        int4   q0 = *(const int4*)(&lds_w[cur][c0]);
        int4   q1 = *(const int4*)(&lds_w[cur][c1]);
        float2 sv = *(const float2*)(szp);
        float4 xa = *(const float4*)(xp0);
        float4 xb = *(const float4*)(xp0 + 4);
        float4 xc = *(const float4*)(xp1);
        float4 xd = *(const float4*)(xp1 + 4);
        xp0 += 32;
        xp1 += 32;
        szp += (size_t)OUT_F * 2;

        const float sc = sv.x;
        const float zp = sv.y - 8.0f * sv.x;   // fold the -8 midpoint into zero

        union { bf16x8 v; uint32_t u[4]; } bf, a0, a1;
        bf.u[0] = pack_bf16((float)q0.x * sc + zp, (float)q0.y * sc + zp);
        bf.u[1] = pack_bf16((float)q0.z * sc + zp, (float)q0.w * sc + zp);
        bf.u[2] = pack_bf16((float)q1.x * sc + zp, (float)q1.y * sc + zp);
        bf.u[3] = pack_bf16((float)q1.z * sc + zp, (float)q1.w * sc + zp);
        a0.u[0] = pack_bf16(xa.x, xa.y);
        a0.u[1] = pack_bf16(xa.z, xa.w);
        a0.u[2] = pack_bf16(xb.x, xb.y);
        a0.u[3] = pack_bf16(xb.z, xb.w);
        a1.u[0] = pack_bf16(xc.x, xc.y);
        a1.u[1] = pack_bf16(xc.z, xc.w);
        a1.u[2] = pack_bf16(xd.x, xd.y);
        a1.u[3] = pack_bf16(xd.z, xd.w);

        acc0 = __builtin_amdgcn_mfma_f32_16x16x32_bf16(a0.v, bf.v, acc0, 0, 0, 0);
        acc1 = __builtin_amdgcn_mfma_f32_16x16x32_bf16(a1.v, bf.v, acc1, 0, 0, 0);
        cur ^= 1;
    }
#undef STAGE

    // epilogue: D col(lane&15)=n, row((lane>>4)*4+i)=m  (verified R0)
    const int ocol = row;
    #pragma unroll
    for (int i = 0; i < 4; ++i) {
        int m0 = lq * 4 + i;
        atomicAdd(&out[(size_t)m0 * OUT_F + ocol], acc0[i]);
        atomicAdd(&out[(size_t)(16 + m0) * OUT_F + ocol], acc1[i]);
    }
}

extern "C" void kernel_launch(void* const* d_in, const int* in_sizes, int n_in,
                              void* d_out, int out_size, void* d_ws, size_t ws_size,
                              hipStream_t stream) {
    const float* x    = (const float*)d_in[0];   // [32, 4096] fp32
    const int*   wq   = (const int*)d_in[1];     // [11008, 4096] int32 (0..15)
    const float* sz   = (const float*)d_in[2];   // [128, 11008, 2] fp32
    const float* bias = (const float*)d_in[3];   // [11008] fp32
    float* out = (float*)d_out;                  // [32, 11008] fp32

    dim3 gi(OUT_F / 256, M_TOK);                 // 43 x 32
    init_out_kernel<<<gi, 256, 0, stream>>>(bias, out);

    dim3 gg((OUT_F / 64) * NSPLIT);              // 172 * 8 = 1376 blocks
    qgemm_kernel<<<gg, 256, 0, stream>>>(x, wq, sz, out);
}